// Round 6
// baseline (755.196 us; speedup 1.0000x reference)
//
#include <hip/hip_runtime.h>

#define NN 64
#define TT 64
#define MM 2
#define VV 25
#define CI 64
#define CO 128
#define EMBH 64

// ws layout (float offsets)
#define WS_EJW 0         // 25*128 = 3200
#define WS_EF  3200      // 64*128 = 8192
#define WS_S   11392     // 128
#define WS_BC  11520     // 128
#define WS_CT  11648     // 64*128 = 8192
#define WS_WT4 19840     // 128*128*4 = 65536 (wt4[c][o][4])
#define WS_H   85888     // 64*64*2*25*128 = 26214400
#define XOUT_ELEMS 26214400

// ---------------- k0a: ej MLP -> ejW fold, plus BN fold ----------------
__global__ void k0a_ej(const float* __restrict__ ej_w1, const float* __restrict__ ej_b1,
                       const float* __restrict__ ej_w2, const float* __restrict__ ej_b2,
                       const float* __restrict__ gcn_w, const float* __restrict__ tcn_b,
                       const float* __restrict__ bn_gamma, const float* __restrict__ bn_beta,
                       const float* __restrict__ bn_mean, const float* __restrict__ bn_var,
                       float* __restrict__ ws) {
  __shared__ float tmp1[VV * EMBH];
  __shared__ float ejs[VV * EMBH];
  int tid = threadIdx.x;
  for (int i = tid; i < VV * EMBH; i += 256)
    tmp1[i] = fmaxf(ej_w1[i] + ej_b1[i & 63], 0.f);
  __syncthreads();
  for (int i = tid; i < VV * EMBH; i += 256) {
    int v = i >> 6, c = i & 63;
    float a = ej_b2[c];
    for (int h = 0; h < EMBH; ++h) a += tmp1[v * EMBH + h] * ej_w2[h * CI + c];
    ejs[i] = fmaxf(a, 0.f);
  }
  __syncthreads();
  for (int i = tid; i < VV * CO; i += 256) {
    int v = i >> 7, o = i & 127;
    float a = 0.f;
    for (int c = 0; c < CI; ++c) a += ejs[v * EMBH + c] * gcn_w[(CI + c) * CO + o];
    ws[WS_EJW + i] = a;
  }
  if (tid < CO) {
    float s = bn_gamma[tid] * rsqrtf(bn_var[tid] + 1e-5f);
    ws[WS_S + tid] = s;
    ws[WS_BC + tid] = tcn_b[tid] * s + bn_beta[tid] - bn_mean[tid] * s;
  }
}

// ---------------- k0b: ef[t][o], one block per t ----------------
__global__ void k0b_ef(const float* __restrict__ ef_w1, const float* __restrict__ ef_b1,
                       const float* __restrict__ ef_w2, const float* __restrict__ ef_b2,
                       float* __restrict__ ws) {
  __shared__ float tf[EMBH];
  int t = blockIdx.x, o = threadIdx.x;
  if (o < EMBH) tf[o] = fmaxf(ef_w1[t * EMBH + o] + ef_b1[o], 0.f);
  __syncthreads();
  float a = ef_b2[o];
#pragma unroll
  for (int h = 0; h < EMBH; ++h) a += tf[h] * ef_w2[h * CO + o];
  ws[WS_EF + t * CO + o] = fmaxf(a, 0.f);
}

// ---------------- k_wt: wt4[(c*128+o)*4+k] = tcn_w[o*384 + c*3 + k] ----------------
__global__ void k_wt(const float* __restrict__ tcn_w, float* __restrict__ wt4) {
  int j = blockIdx.x * 256 + threadIdx.x;
  if (j >= CO * CO) return;
  int o = j & 127, c = j >> 7;
  float4 w;
  w.x = tcn_w[o * (CO * 3) + c * 3 + 0];
  w.y = tcn_w[o * (CO * 3) + c * 3 + 1];
  w.z = tcn_w[o * (CO * 3) + c * 3 + 2];
  w.w = 0.f;
  ((float4*)wt4)[j] = w;
}

// ---------------- k1_ct: ct[t][o] = conv(ef)[o,t]*s[o] + bc[o] ----------------
__global__ void k1_ct(const float* __restrict__ ws_ro, float* __restrict__ ct_out) {
  __shared__ float ef3[3 * CO];
  int t = blockIdx.x, o = threadIdx.x;
  for (int i = o; i < 3 * CO; i += 128) {
    int k = i >> 7, c = i & 127, tt = t + k - 1;
    ef3[i] = (tt >= 0 && tt < TT) ? ws_ro[WS_EF + tt * CO + c] : 0.f;
  }
  __syncthreads();
  const float4* w4 = (const float4*)(ws_ro + WS_WT4);
  float a = 0.f;
  for (int c = 0; c < CO; ++c) {
    float4 wq = w4[c * CO + o];
    a += ef3[c] * wq.x + ef3[CO + c] * wq.y + ef3[2 * CO + c] * wq.z;
  }
  ct_out[t * CO + o] = a * ws_ro[WS_S + o] + ws_ro[WS_BC + o];
}

// ---------------- GCN v2: split-c phase1 (wreg[32]/thread), per (n,t,m) ----------------
__global__ void __launch_bounds__(256, 6) k_gcn(const float* __restrict__ x, const float* __restrict__ G,
                                                const float* __restrict__ gcn_w, const float* __restrict__ gcn_b,
                                                const float* __restrict__ ejW, float* __restrict__ h_ws) {
  __shared__ float xs[VV * CI];     // 1600
  __shared__ float Gs[VV * VV];     // 625
  __shared__ float Ps[2][VV * CO];  // 6400
  int ntm = blockIdx.x;
  int tid = threadIdx.x;
  const float* xb = x + (size_t)ntm * (VV * CI);
  for (int i = tid; i < VV * CI; i += 256) xs[i] = xb[i];
  const float* Gb = G + (size_t)ntm * (VV * VV);
  for (int i = tid; i < VV * VV; i += 256) Gs[i] = Gb[i];
  int o = tid & 127, h = tid >> 7;  // h: which c-half this thread owns
  float wreg[32];
#pragma unroll
  for (int c = 0; c < 32; ++c) wreg[c] = gcn_w[(h * 32 + c) * CO + o];
  __syncthreads();
  // phase1: partial P over c-half h, all 25 rows
  for (int v = 0; v < VV; ++v) {
    float a = h ? 0.f : ejW[v * CO + o];  // wave-uniform branch
    const float4* xv = (const float4*)&xs[v * CI + h * 32];
#pragma unroll
    for (int c4 = 0; c4 < 8; ++c4) {
      float4 q = xv[c4];
      a += q.x * wreg[4 * c4] + q.y * wreg[4 * c4 + 1] + q.z * wreg[4 * c4 + 2] + q.w * wreg[4 * c4 + 3];
    }
    Ps[h][v * CO + o] = a;
  }
  __syncthreads();
  float bo = gcn_b[o];
  float* hb = h_ws + (size_t)ntm * (VV * CO);
  for (int u = h; u < VV; u += 2) {
    float a = bo;
#pragma unroll
    for (int v = 0; v < VV; ++v)
      a += Gs[u * VV + v] * (Ps[0][v * CO + o] + Ps[1][v * CO + o]);
    hb[u * CO + o] = fmaxf(a, 0.f);
  }
}

// ---------------- TCN v2: 512 thr, acc[16]/thread, per (n,m,v) ----------------
__global__ void __launch_bounds__(512, 6) k_tcn(const float* __restrict__ ws_ro,
                                                float* __restrict__ out) {
  __shared__ float hs[CO][68];  // [c][t+1], row 272 B (16B-aligned)
  int b = blockIdx.x;
  int n = b / (MM * VV), r = b % (MM * VV), m = r / VV, v = r % VV;
  int tid = threadIdx.x;
  const float* hbase = ws_ro + WS_H + ((size_t)((n * TT) * MM + m) * VV + v) * CO;
  for (int i = tid; i < TT * CO; i += 512) {
    int t = i >> 7, c = i & 127;
    hs[c][t + 1] = hbase[(size_t)t * (MM * VV * CO) + c];
  }
  if (tid < CO) { hs[tid][0] = 0.f; hs[tid][65] = 0.f; hs[tid][66] = 0.f; hs[tid][67] = 0.f; }
  __syncthreads();
  int o = tid & 127, ch = tid >> 7, t0 = ch << 4;  // 4 chunks of 16 t's
  float acc[16];
#pragma unroll
  for (int t = 0; t < 16; ++t) acc[t] = 0.f;
  const float4* w4 = (const float4*)(ws_ro + WS_WT4) + o;
  float4 w = w4[0];
  for (int c = 0; c < CO; ++c) {
    float4 wn = w;
    if (c < CO - 1) wn = w4[(c + 1) * CO];          // prefetch next c's weights
    const float4* hp = (const float4*)&hs[c][t0];   // wave-uniform -> broadcast
    float4 q0 = hp[0], q1 = hp[1], q2 = hp[2], q3 = hp[3], q4 = hp[4];
    float w0 = w.x, w1 = w.y, w2 = w.z;
#define STEP(g, qa, qb)                                   \
    acc[4*g+0] += qa.x * w0 + qa.y * w1 + qa.z * w2;      \
    acc[4*g+1] += qa.y * w0 + qa.z * w1 + qa.w * w2;      \
    acc[4*g+2] += qa.z * w0 + qa.w * w1 + qb.x * w2;      \
    acc[4*g+3] += qa.w * w0 + qb.x * w1 + qb.y * w2;
    STEP(0, q0, q1) STEP(1, q1, q2) STEP(2, q2, q3) STEP(3, q3, q4)
#undef STEP
    w = wn;
  }
  float so = ws_ro[WS_S + o];
  float* ob = out + ((size_t)((n * TT) * MM + m) * VV + v) * CO;
#pragma unroll
  for (int t = 0; t < 16; ++t) {
    int gt = t0 + t;
    ob[(size_t)gt * (MM * VV * CO) + o] = fmaxf(acc[t] * so + ws_ro[WS_CT + gt * CO + o], 0.f);
  }
}

// ---------------- ADJ: g_out[n,t,m,u,o] ----------------
__global__ void k_adj(const float* __restrict__ G, const float* __restrict__ adj_w,
                      const float* __restrict__ adj_b, float* __restrict__ gout) {
  __shared__ float Gs3[3 * VV * VV];
  __shared__ float wls[VV * VV * 3];
  int ntm = blockIdx.x;
  int n = ntm / (TT * MM), r = ntm % (TT * MM), t = r / MM, m = r % MM;
  int tid = threadIdx.x;
  for (int i = tid; i < 3 * VV * VV; i += 256) {
    int k = i / (VV * VV), e = i % (VV * VV), tt = t + k - 1;
    Gs3[i] = (tt >= 0 && tt < TT) ? G[((size_t)((n * TT + tt) * MM + m)) * (VV * VV) + e] : 0.f;
  }
  for (int i = tid; i < VV * VV * 3; i += 256) wls[i] = adj_w[i];
  __syncthreads();
  for (int e = tid; e < VV * VV; e += 256) {
    int u = e / VV, o = e % VV;
    float a = adj_b[o];
#pragma unroll
    for (int i = 0; i < VV; ++i) {
      a += Gs3[u * VV + i] * wls[o * 75 + i * 3]
         + Gs3[VV * VV + u * VV + i] * wls[o * 75 + i * 3 + 1]
         + Gs3[2 * VV * VV + u * VV + i] * wls[o * 75 + i * 3 + 2];
    }
    gout[(size_t)ntm * (VV * VV) + e] = a;
  }
}

extern "C" void kernel_launch(void* const* d_in, const int* in_sizes, int n_in,
                              void* d_out, int out_size, void* d_ws, size_t ws_size,
                              hipStream_t stream) {
  const float* x     = (const float*)d_in[0];
  const float* G     = (const float*)d_in[1];
  const float* ej_w1 = (const float*)d_in[2];
  const float* ej_b1 = (const float*)d_in[3];
  const float* ej_w2 = (const float*)d_in[4];
  const float* ej_b2 = (const float*)d_in[5];
  const float* ef_w1 = (const float*)d_in[6];
  const float* ef_b1 = (const float*)d_in[7];
  const float* ef_w2 = (const float*)d_in[8];
  const float* ef_b2 = (const float*)d_in[9];
  const float* gcn_w = (const float*)d_in[10];
  const float* gcn_b = (const float*)d_in[11];
  const float* tcn_w = (const float*)d_in[12];
  const float* tcn_b = (const float*)d_in[13];
  const float* bn_g  = (const float*)d_in[14];
  const float* bn_b  = (const float*)d_in[15];
  const float* bn_m  = (const float*)d_in[16];
  const float* bn_v  = (const float*)d_in[17];
  const float* adj_w = (const float*)d_in[18];
  const float* adj_b = (const float*)d_in[19];
  float* out = (float*)d_out;
  float* ws  = (float*)d_ws;

  k0a_ej<<<1, 256, 0, stream>>>(ej_w1, ej_b1, ej_w2, ej_b2, gcn_w, tcn_b, bn_g, bn_b, bn_m, bn_v, ws);
  k0b_ef<<<TT, CO, 0, stream>>>(ef_w1, ef_b1, ef_w2, ef_b2, ws);
  k_wt<<<(CO * CO + 255) / 256, 256, 0, stream>>>(tcn_w, ws + WS_WT4);
  k1_ct<<<TT, CO, 0, stream>>>(ws, ws + WS_CT);
  k_gcn<<<NN * TT * MM, 256, 0, stream>>>(x, G, gcn_w, gcn_b, ws + WS_EJW, ws + WS_H);
  k_tcn<<<NN * MM * VV, 512, 0, stream>>>(ws, out);
  k_adj<<<NN * TT * MM, 256, 0, stream>>>(G, adj_w, adj_b, out + XOUT_ELEMS);
}

// Round 8
// 681.136 us; speedup vs baseline: 1.1087x; 1.1087x over previous
//
#include <hip/hip_runtime.h>

#define NN 64
#define TT 64
#define MM 2
#define VV 25
#define CI 64
#define CO 128
#define EMBH 64

// ws layout (float offsets)
#define WS_EJW 0         // 25*128 = 3200
#define WS_EF  3200      // 64*128 = 8192
#define WS_S   11392     // 128
#define WS_BC  11520     // 128
#define WS_CT  11648     // 64*128 = 8192
#define WS_WT4 19840     // 129*128*4 = 66048 (wt4[c][o][4], c padded to 129)
#define WS_H   85888     // 64*64*2*25*128 = 26214400
#define XOUT_ELEMS 26214400

// ---------------- k0a: ej MLP -> ejW fold, plus BN fold ----------------
__global__ void k0a_ej(const float* __restrict__ ej_w1, const float* __restrict__ ej_b1,
                       const float* __restrict__ ej_w2, const float* __restrict__ ej_b2,
                       const float* __restrict__ gcn_w, const float* __restrict__ tcn_b,
                       const float* __restrict__ bn_gamma, const float* __restrict__ bn_beta,
                       const float* __restrict__ bn_mean, const float* __restrict__ bn_var,
                       float* __restrict__ ws) {
  __shared__ float tmp1[VV * EMBH];
  __shared__ float ejs[VV * EMBH];
  int tid = threadIdx.x;
  for (int i = tid; i < VV * EMBH; i += 256)
    tmp1[i] = fmaxf(ej_w1[i] + ej_b1[i & 63], 0.f);
  __syncthreads();
  for (int i = tid; i < VV * EMBH; i += 256) {
    int v = i >> 6, c = i & 63;
    float a = ej_b2[c];
    for (int h = 0; h < EMBH; ++h) a = fmaf(tmp1[v * EMBH + h], ej_w2[h * CI + c], a);
    ejs[i] = fmaxf(a, 0.f);
  }
  __syncthreads();
  for (int i = tid; i < VV * CO; i += 256) {
    int v = i >> 7, o = i & 127;
    float a = 0.f;
    for (int c = 0; c < CI; ++c) a = fmaf(ejs[v * EMBH + c], gcn_w[(CI + c) * CO + o], a);
    ws[WS_EJW + i] = a;
  }
  if (tid < CO) {
    float s = bn_gamma[tid] * rsqrtf(bn_var[tid] + 1e-5f);
    ws[WS_S + tid] = s;
    ws[WS_BC + tid] = tcn_b[tid] * s + bn_beta[tid] - bn_mean[tid] * s;
  }
}

// ---------------- k0b: ef[t][o], one block per t ----------------
__global__ void k0b_ef(const float* __restrict__ ef_w1, const float* __restrict__ ef_b1,
                       const float* __restrict__ ef_w2, const float* __restrict__ ef_b2,
                       float* __restrict__ ws) {
  __shared__ float tf[EMBH];
  int t = blockIdx.x, o = threadIdx.x;
  if (o < EMBH) tf[o] = fmaxf(ef_w1[t * EMBH + o] + ef_b1[o], 0.f);
  __syncthreads();
  float a = ef_b2[o];
#pragma unroll
  for (int h = 0; h < EMBH; ++h) a = fmaf(tf[h], ef_w2[h * CO + o], a);
  ws[WS_EF + t * CO + o] = fmaxf(a, 0.f);
}

// ---------------- k_wt: wt4[(c*128+o)*4+k] = tcn_w[o*384+c*3+k]; c==128 row zeroed ----------------
__global__ void k_wt(const float* __restrict__ tcn_w, float* __restrict__ wt4) {
  int j = blockIdx.x * 256 + threadIdx.x;
  if (j >= 129 * CO) return;
  int o = j & 127, c = j >> 7;
  float4 w = {0.f, 0.f, 0.f, 0.f};
  if (c < CO) {
    w.x = tcn_w[o * (CO * 3) + c * 3 + 0];
    w.y = tcn_w[o * (CO * 3) + c * 3 + 1];
    w.z = tcn_w[o * (CO * 3) + c * 3 + 2];
  }
  ((float4*)wt4)[j] = w;
}

// ---------------- k1_ct: ct[t][o] = conv(ef)[o,t]*s[o] + bc[o] ----------------
__global__ void k1_ct(const float* __restrict__ ws_ro, float* __restrict__ ct_out) {
  __shared__ float ef3[3 * CO];
  int t = blockIdx.x, o = threadIdx.x;
  for (int i = o; i < 3 * CO; i += 128) {
    int k = i >> 7, c = i & 127, tt = t + k - 1;
    ef3[i] = (tt >= 0 && tt < TT) ? ws_ro[WS_EF + tt * CO + c] : 0.f;
  }
  __syncthreads();
  const float4* w4 = (const float4*)(ws_ro + WS_WT4);
  float a = 0.f;
  for (int c = 0; c < CO; ++c) {
    float4 wq = w4[c * CO + o];
    a = fmaf(ef3[c], wq.x, a);
    a = fmaf(ef3[CO + c], wq.y, a);
    a = fmaf(ef3[2 * CO + c], wq.z, a);
  }
  ct_out[t * CO + o] = fmaf(a, ws_ro[WS_S + o], ws_ro[WS_BC + o]);
}

// ---------------- GCN v3: split-c phase1, reg-psum phase2, per (n,t,m) ----------------
__global__ void __launch_bounds__(256, 4) k_gcn(const float* __restrict__ x, const float* __restrict__ G,
                                                const float* __restrict__ gcn_w, const float* __restrict__ gcn_b,
                                                const float* __restrict__ ejW, float* __restrict__ h_ws) {
  __shared__ float xs[VV * CI];     // 1600
  __shared__ float Gs[VV * VV];     // 625
  __shared__ float Ps[2][VV * CO];  // 6400
  int ntm = blockIdx.x;
  int tid = threadIdx.x;
  const float* xb = x + (size_t)ntm * (VV * CI);
  for (int i = tid; i < VV * CI; i += 256) xs[i] = xb[i];
  const float* Gb = G + (size_t)ntm * (VV * VV);
  for (int i = tid; i < VV * VV; i += 256) Gs[i] = Gb[i];
  int o = tid & 127, h = tid >> 7;  // h: c-half owned by this thread
  float wreg[32];
#pragma unroll
  for (int c = 0; c < 32; ++c) wreg[c] = gcn_w[(h * 32 + c) * CO + o];
  __syncthreads();
  // phase1: partial P over c-half h, all 25 rows
  for (int v = 0; v < VV; ++v) {
    float a = h ? 0.f : ejW[v * CO + o];  // wave-uniform branch
    const float4* xv = (const float4*)&xs[v * CI + h * 32];
#pragma unroll
    for (int c4 = 0; c4 < 8; ++c4) {
      float4 q = xv[c4];
      a = fmaf(q.x, wreg[4 * c4 + 0], a);
      a = fmaf(q.y, wreg[4 * c4 + 1], a);
      a = fmaf(q.z, wreg[4 * c4 + 2], a);
      a = fmaf(q.w, wreg[4 * c4 + 3], a);
    }
    Ps[h][v * CO + o] = a;
  }
  __syncthreads();
  // phase2: psum in registers, G reads are LDS broadcasts
  float psum[VV];
#pragma unroll
  for (int v = 0; v < VV; ++v) psum[v] = Ps[0][v * CO + o] + Ps[1][v * CO + o];
  float bo = gcn_b[o];
  float* hb = h_ws + (size_t)ntm * (VV * CO);
  for (int u = h; u < VV; u += 2) {
    float a = bo;
#pragma unroll
    for (int v = 0; v < VV; ++v) a = fmaf(Gs[u * VV + v], psum[v], a);
    hb[u * CO + o] = fmaxf(a, 0.f);
  }
}

// ---------------- TCN v3: 512 thr, acc[16], explicit fmaf, per (n,m,v) ----------------
__global__ void __launch_bounds__(512, 6) k_tcn(const float* __restrict__ ws_ro,
                                                float* __restrict__ out) {
  __shared__ float hs[CO][68];  // [c][t+1], row 272 B (16B-aligned)
  int b = blockIdx.x;
  int n = b / (MM * VV), r = b % (MM * VV), m = r / VV, v = r % VV;
  int tid = threadIdx.x;
  const float* hbase = ws_ro + WS_H + ((size_t)((n * TT) * MM + m) * VV + v) * CO;
  for (int i = tid; i < TT * CO; i += 512) {
    int t = i >> 7, c = i & 127;
    hs[c][t + 1] = hbase[(size_t)t * (MM * VV * CO) + c];
  }
  if (tid < CO) { hs[tid][0] = 0.f; hs[tid][65] = 0.f; hs[tid][66] = 0.f; hs[tid][67] = 0.f; }
  __syncthreads();
  int o = tid & 127, ch = tid >> 7, t0 = ch << 4;  // 4 chunks of 16 t's
  float acc[16];
#pragma unroll
  for (int t = 0; t < 16; ++t) acc[t] = 0.f;
  const float4* w4 = (const float4*)(ws_ro + WS_WT4) + o;
  float4 w = w4[0];
  for (int c = 0; c < CO; ++c) {
    float4 wn = w4[(c + 1) * CO];                   // unconditional (padded row 128)
    const float4* hp = (const float4*)&hs[c][t0];   // wave-uniform -> broadcast
    float4 q0 = hp[0], q1 = hp[1], q2 = hp[2], q3 = hp[3], q4 = hp[4];
    float w0 = w.x, w1 = w.y, w2 = w.z;
#define STEP(g, qa, qb)                                                      \
    acc[4*g+0] = fmaf(qa.x, w0, acc[4*g+0]);                                 \
    acc[4*g+0] = fmaf(qa.y, w1, acc[4*g+0]);                                 \
    acc[4*g+0] = fmaf(qa.z, w2, acc[4*g+0]);                                 \
    acc[4*g+1] = fmaf(qa.y, w0, acc[4*g+1]);                                 \
    acc[4*g+1] = fmaf(qa.z, w1, acc[4*g+1]);                                 \
    acc[4*g+1] = fmaf(qa.w, w2, acc[4*g+1]);                                 \
    acc[4*g+2] = fmaf(qa.z, w0, acc[4*g+2]);                                 \
    acc[4*g+2] = fmaf(qa.w, w1, acc[4*g+2]);                                 \
    acc[4*g+2] = fmaf(qb.x, w2, acc[4*g+2]);                                 \
    acc[4*g+3] = fmaf(qa.w, w0, acc[4*g+3]);                                 \
    acc[4*g+3] = fmaf(qb.x, w1, acc[4*g+3]);                                 \
    acc[4*g+3] = fmaf(qb.y, w2, acc[4*g+3]);
    STEP(0, q0, q1) STEP(1, q1, q2) STEP(2, q2, q3) STEP(3, q3, q4)
#undef STEP
    w = wn;
  }
  float so = ws_ro[WS_S + o];
  float* ob = out + ((size_t)((n * TT) * MM + m) * VV + v) * CO;
#pragma unroll
  for (int t = 0; t < 16; ++t) {
    int gt = t0 + t;
    ob[(size_t)gt * (MM * VV * CO) + o] = fmaxf(fmaf(acc[t], so, ws_ro[WS_CT + gt * CO + o]), 0.f);
  }
}

// ---------------- ADJ: g_out[n,t,m,u,o] ----------------
__global__ void k_adj(const float* __restrict__ G, const float* __restrict__ adj_w,
                      const float* __restrict__ adj_b, float* __restrict__ gout) {
  __shared__ float Gs3[3 * VV * VV];
  __shared__ float wls[VV * VV * 3];
  int ntm = blockIdx.x;
  int n = ntm / (TT * MM), r = ntm % (TT * MM), t = r / MM, m = r % MM;
  int tid = threadIdx.x;
  for (int i = tid; i < 3 * VV * VV; i += 256) {
    int k = i / (VV * VV), e = i % (VV * VV), tt = t + k - 1;
    Gs3[i] = (tt >= 0 && tt < TT) ? G[((size_t)((n * TT + tt) * MM + m)) * (VV * VV) + e] : 0.f;
  }
  for (int i = tid; i < VV * VV * 3; i += 256) wls[i] = adj_w[i];
  __syncthreads();
  for (int e = tid; e < VV * VV; e += 256) {
    int u = e / VV, o = e % VV;
    float a = adj_b[o];
#pragma unroll
    for (int i = 0; i < VV; ++i) {
      a = fmaf(Gs3[u * VV + i], wls[o * 75 + i * 3 + 0], a);
      a = fmaf(Gs3[VV * VV + u * VV + i], wls[o * 75 + i * 3 + 1], a);
      a = fmaf(Gs3[2 * VV * VV + u * VV + i], wls[o * 75 + i * 3 + 2], a);
    }
    gout[(size_t)ntm * (VV * VV) + e] = a;
  }
}

extern "C" void kernel_launch(void* const* d_in, const int* in_sizes, int n_in,
                              void* d_out, int out_size, void* d_ws, size_t ws_size,
                              hipStream_t stream) {
  const float* x     = (const float*)d_in[0];
  const float* G     = (const float*)d_in[1];
  const float* ej_w1 = (const float*)d_in[2];
  const float* ej_b1 = (const float*)d_in[3];
  const float* ej_w2 = (const float*)d_in[4];
  const float* ej_b2 = (const float*)d_in[5];
  const float* ef_w1 = (const float*)d_in[6];
  const float* ef_b1 = (const float*)d_in[7];
  const float* ef_w2 = (const float*)d_in[8];
  const float* ef_b2 = (const float*)d_in[9];
  const float* gcn_w = (const float*)d_in[10];
  const float* gcn_b = (const float*)d_in[11];
  const float* tcn_w = (const float*)d_in[12];
  const float* tcn_b = (const float*)d_in[13];
  const float* bn_g  = (const float*)d_in[14];
  const float* bn_b  = (const float*)d_in[15];
  const float* bn_m  = (const float*)d_in[16];
  const float* bn_v  = (const float*)d_in[17];
  const float* adj_w = (const float*)d_in[18];
  const float* adj_b = (const float*)d_in[19];
  float* out = (float*)d_out;
  float* ws  = (float*)d_ws;

  k0a_ej<<<1, 256, 0, stream>>>(ej_w1, ej_b1, ej_w2, ej_b2, gcn_w, tcn_b, bn_g, bn_b, bn_m, bn_v, ws);
  k0b_ef<<<TT, CO, 0, stream>>>(ef_w1, ef_b1, ef_w2, ef_b2, ws);
  k_wt<<<(129 * CO + 255) / 256, 256, 0, stream>>>(tcn_w, ws + WS_WT4);
  k1_ct<<<TT, CO, 0, stream>>>(ws, ws + WS_CT);
  k_gcn<<<NN * TT * MM, 256, 0, stream>>>(x, G, gcn_w, gcn_b, ws + WS_EJW, ws + WS_H);
  k_tcn<<<NN * MM * VV, 512, 0, stream>>>(ws, out);
  k_adj<<<NN * TT * MM, 256, 0, stream>>>(G, adj_w, adj_b, out + XOUT_ELEMS);
}

// Round 10
// 518.411 us; speedup vs baseline: 1.4568x; 1.3139x over previous
//
#include <hip/hip_runtime.h>

#define NN 64
#define TT 64
#define MM 2
#define VV 25
#define CI 64
#define CO 128
#define EMBH 64

typedef __attribute__((ext_vector_type(8))) short short8;
typedef __attribute__((ext_vector_type(4))) float f32x4;

// ws layout (float offsets)
#define WS_EJW 0          // 3200
#define WS_EF  3200       // 8192
#define WS_S   11392      // 128
#define WS_BC  11520      // 128
#define WS_CT  11648      // 8192
#define WS_WH  19840      // 3*128*128 bf16 = 49152 ushort = 24576 floats
#define WS_WL  44416      // 24576 floats
#define WS_HHI 68992      // 26214400 bf16 = 13107200 floats
#define WS_HLO 13176192   // 13107200 floats
#define XOUT_ELEMS 26214400

__device__ __forceinline__ unsigned short bf16_rne(float f) {
  unsigned u = __float_as_uint(f);
  unsigned r = u + 0x7FFFu + ((u >> 16) & 1u);
  return (unsigned short)(r >> 16);
}
__device__ __forceinline__ float bf16_to_f(unsigned short h) {
  return __uint_as_float((unsigned)h << 16);
}

// ---------------- k0a: ej MLP -> ejW fold, plus BN fold ----------------
__global__ void k0a_ej(const float* __restrict__ ej_w1, const float* __restrict__ ej_b1,
                       const float* __restrict__ ej_w2, const float* __restrict__ ej_b2,
                       const float* __restrict__ gcn_w, const float* __restrict__ tcn_b,
                       const float* __restrict__ bn_gamma, const float* __restrict__ bn_beta,
                       const float* __restrict__ bn_mean, const float* __restrict__ bn_var,
                       float* __restrict__ ws) {
  __shared__ float tmp1[VV * EMBH];
  __shared__ float ejs[VV * EMBH];
  int tid = threadIdx.x;
  for (int i = tid; i < VV * EMBH; i += 256)
    tmp1[i] = fmaxf(ej_w1[i] + ej_b1[i & 63], 0.f);
  __syncthreads();
  for (int i = tid; i < VV * EMBH; i += 256) {
    int v = i >> 6, c = i & 63;
    float a = ej_b2[c];
    for (int h = 0; h < EMBH; ++h) a = fmaf(tmp1[v * EMBH + h], ej_w2[h * CI + c], a);
    ejs[i] = fmaxf(a, 0.f);
  }
  __syncthreads();
  for (int i = tid; i < VV * CO; i += 256) {
    int v = i >> 7, o = i & 127;
    float a = 0.f;
    for (int c = 0; c < CI; ++c) a = fmaf(ejs[v * EMBH + c], gcn_w[(CI + c) * CO + o], a);
    ws[WS_EJW + i] = a;
  }
  if (tid < CO) {
    float s = bn_gamma[tid] * rsqrtf(bn_var[tid] + 1e-5f);
    ws[WS_S + tid] = s;
    ws[WS_BC + tid] = tcn_b[tid] * s + bn_beta[tid] - bn_mean[tid] * s;
  }
}

// ---------------- k0b: ef[t][o] ----------------
__global__ void k0b_ef(const float* __restrict__ ef_w1, const float* __restrict__ ef_b1,
                       const float* __restrict__ ef_w2, const float* __restrict__ ef_b2,
                       float* __restrict__ ws) {
  __shared__ float tf[EMBH];
  int t = blockIdx.x, o = threadIdx.x;
  if (o < EMBH) tf[o] = fmaxf(ef_w1[t * EMBH + o] + ef_b1[o], 0.f);
  __syncthreads();
  float a = ef_b2[o];
#pragma unroll
  for (int h = 0; h < EMBH; ++h) a = fmaf(tf[h], ef_w2[h * CO + o], a);
  ws[WS_EF + t * CO + o] = fmaxf(a, 0.f);
}

// ---------------- k_wt2: split tcn_w -> bf16 hi/lo, layout [s][o][c] ----------------
__global__ void k_wt2(const float* __restrict__ tcn_w, float* __restrict__ ws) {
  int j = blockIdx.x * 256 + threadIdx.x;
  if (j >= 3 * CO * CO) return;
  int s = j >> 14, rr = j & 16383, o = rr >> 7, c = rr & 127;
  float f = tcn_w[o * (CO * 3) + c * 3 + s];
  unsigned short hi = bf16_rne(f);
  float lo = f - bf16_to_f(hi);
  ((unsigned short*)(ws + WS_WH))[j] = hi;
  ((unsigned short*)(ws + WS_WL))[j] = bf16_rne(lo);
}

// ---------------- k1_ct: ct[t][o] = conv(ef)[o,t]*s[o] + bc[o] ----------------
__global__ void k1_ct(const float* __restrict__ tcn_w, const float* __restrict__ ws_ro,
                      float* __restrict__ ct_out) {
  __shared__ float ef3[3 * CO];
  int t = blockIdx.x, o = threadIdx.x;
  for (int i = o; i < 3 * CO; i += 128) {
    int k = i >> 7, c = i & 127, tt = t + k - 1;
    ef3[i] = (tt >= 0 && tt < TT) ? ws_ro[WS_EF + tt * CO + c] : 0.f;
  }
  __syncthreads();
  const float* wp = tcn_w + o * (CO * 3);
  float a = 0.f;
  for (int c = 0; c < CO; ++c) {
    a = fmaf(ef3[c], wp[c * 3 + 0], a);
    a = fmaf(ef3[CO + c], wp[c * 3 + 1], a);
    a = fmaf(ef3[2 * CO + c], wp[c * 3 + 2], a);
  }
  ct_out[t * CO + o] = fmaf(a, ws_ro[WS_S + o], ws_ro[WS_BC + o]);
}

// ---------------- GCN v3 + bf16-split epilogue, per (n,t,m) ----------------
__global__ void __launch_bounds__(256, 4) k_gcn(const float* __restrict__ x, const float* __restrict__ G,
                                                const float* __restrict__ gcn_w, const float* __restrict__ gcn_b,
                                                const float* __restrict__ ejW, float* __restrict__ ws) {
  __shared__ float xs[VV * CI];
  __shared__ float Gs[VV * VV];
  __shared__ float Ps[2][VV * CO];
  int ntm = blockIdx.x;
  int tid = threadIdx.x;
  const float* xb = x + (size_t)ntm * (VV * CI);
  for (int i = tid; i < VV * CI; i += 256) xs[i] = xb[i];
  const float* Gb = G + (size_t)ntm * (VV * VV);
  for (int i = tid; i < VV * VV; i += 256) Gs[i] = Gb[i];
  int o = tid & 127, h = tid >> 7;
  float wreg[32];
#pragma unroll
  for (int c = 0; c < 32; ++c) wreg[c] = gcn_w[(h * 32 + c) * CO + o];
  __syncthreads();
  for (int v = 0; v < VV; ++v) {
    float a = h ? 0.f : ejW[v * CO + o];
    const float4* xv = (const float4*)&xs[v * CI + h * 32];
#pragma unroll
    for (int c4 = 0; c4 < 8; ++c4) {
      float4 q = xv[c4];
      a = fmaf(q.x, wreg[4 * c4 + 0], a);
      a = fmaf(q.y, wreg[4 * c4 + 1], a);
      a = fmaf(q.z, wreg[4 * c4 + 2], a);
      a = fmaf(q.w, wreg[4 * c4 + 3], a);
    }
    Ps[h][v * CO + o] = a;
  }
  __syncthreads();
  float psum[VV];
#pragma unroll
  for (int v = 0; v < VV; ++v) psum[v] = Ps[0][v * CO + o] + Ps[1][v * CO + o];
  float bo = gcn_b[o];
  unsigned short* hh_g = (unsigned short*)(ws + WS_HHI);
  unsigned short* hl_g = (unsigned short*)(ws + WS_HLO);
  size_t base = (size_t)ntm * (VV * CO);
  for (int u = h; u < VV; u += 2) {
    float a = bo;
#pragma unroll
    for (int v = 0; v < VV; ++v) a = fmaf(Gs[u * VV + v], psum[v], a);
    float y = fmaxf(a, 0.f);
    unsigned short hi = bf16_rne(y);
    float lo = y - bf16_to_f(hi);
    hh_g[base + u * CO + o] = hi;
    hl_g[base + u * CO + o] = bf16_rne(lo);
  }
}

// ---------------- TCN v4: split-bf16 MFMA GEMM, per (n,m,v) ----------------
// C[t][o] = sum_{s,c} h[t+s-1][c] * w[o][c][s];  3-term split: AhBh + AlBh + AhBl
__global__ void __launch_bounds__(512) k_tcn(const float* __restrict__ ws_ro,
                                             float* __restrict__ out) {
  __shared__ __align__(16) unsigned short h2[2 * 68 * 128];  // hi @0, lo @8704; row = t+1
  int b = blockIdx.x;
  int n = b / (MM * VV), r = b % (MM * VV), m = r / VV, v = r % VV;
  int tid = threadIdx.x;
  const unsigned short* hh_g = (const unsigned short*)(ws_ro + WS_HHI);
  const unsigned short* hl_g = (const unsigned short*)(ws_ro + WS_HLO);
  size_t gbase = ((size_t)(n * TT * MM + m) * VV + v) * CO;  // elem offset of t=0 row
  // stage h (rows t=0..63 -> lds rows 1..64), XOR-swizzled
#pragma unroll
  for (int arr = 0; arr < 2; ++arr) {
    const unsigned short* src = arr ? hl_g : hh_g;
#pragma unroll
    for (int rep = 0; rep < 2; ++rep) {
      int task = rep * 512 + tid;       // 0..1023
      int t = task >> 4, chunk = task & 15;
      int row = t + 1;
      int4 val = *(const int4*)(src + gbase + (size_t)t * (MM * VV * CO) + chunk * 8);
      int elem = arr * 8704 + row * 128 + ((((chunk * 16) ^ ((row & 7) << 4))) >> 1);
      *(int4*)(&h2[elem]) = val;
    }
  }
  if (tid < 64) {  // zero pad rows 0 (t=-1) and 65 (t=64), both arrays
    int arr = tid >> 5, rr = (tid >> 4) & 1, chunk = tid & 15;
    int row = rr ? 65 : 0;
    int elem = arr * 8704 + row * 128 + ((((chunk * 16) ^ ((row & 7) << 4))) >> 1);
    int4 z = {0, 0, 0, 0};
    *(int4*)(&h2[elem]) = z;
  }
  __syncthreads();
  int w = tid >> 6, l = tid & 63;   // wave = o-tile
  int o0 = w * 16, lm = l & 15, lg = l >> 4;
  // B prologue: this wave's o-tile, all (s,ks), hi+lo -> 96 VGPRs
  const unsigned short* wh_g = (const unsigned short*)(ws_ro + WS_WH);
  const unsigned short* wl_g = (const unsigned short*)(ws_ro + WS_WL);
  short8 bh[3][4], bl[3][4];
#pragma unroll
  for (int s = 0; s < 3; ++s)
#pragma unroll
    for (int ks = 0; ks < 4; ++ks) {
      int idx = (s * CO + o0 + lm) * CO + ks * 32 + lg * 8;
      bh[s][ks] = *(const short8*)(wh_g + idx);
      bl[s][ks] = *(const short8*)(wl_g + idx);
    }
  float so = ws_ro[WS_S + o0 + lm];
  float* ob = out + gbase;
  for (int tq = 0; tq < 4; ++tq) {
    f32x4 ahh = {0.f, 0.f, 0.f, 0.f}, alh = {0.f, 0.f, 0.f, 0.f}, ahl = {0.f, 0.f, 0.f, 0.f};
#pragma unroll
    for (int s = 0; s < 3; ++s) {
      int row = tq * 16 + lm + s;            // lds row = t0 + m + s  (t = t0+m, src row t+s-1 -> lds +1)
      int rbase = row * 128, sw = (row & 7) << 4;
#pragma unroll
      for (int ks = 0; ks < 4; ++ks) {
        int eo = rbase + (((ks * 64 + lg * 16) ^ sw) >> 1);
        short8 Ah = *(const short8*)(&h2[eo]);
        short8 Al = *(const short8*)(&h2[8704 + eo]);
        ahh = __builtin_amdgcn_mfma_f32_16x16x32_bf16(Ah, bh[s][ks], ahh, 0, 0, 0);
        alh = __builtin_amdgcn_mfma_f32_16x16x32_bf16(Al, bh[s][ks], alh, 0, 0, 0);
        ahl = __builtin_amdgcn_mfma_f32_16x16x32_bf16(Ah, bl[s][ks], ahl, 0, 0, 0);
      }
    }
#pragma unroll
    for (int rr = 0; rr < 4; ++rr) {
      int t = tq * 16 + lg * 4 + rr;         // C/D: col=lane&15, row=(lane>>4)*4+reg  [m89]
      float acc = ahh[rr] + alh[rr] + ahl[rr];
      float y = fmaxf(fmaf(acc, so, ws_ro[WS_CT + t * CO + o0 + lm]), 0.f);
      ob[(size_t)t * (MM * VV * CO) + o0 + lm] = y;
    }
  }
}

// ---------------- ADJ ----------------
__global__ void k_adj(const float* __restrict__ G, const float* __restrict__ adj_w,
                      const float* __restrict__ adj_b, float* __restrict__ gout) {
  __shared__ float Gs3[3 * VV * VV];
  __shared__ float wls[VV * VV * 3];
  int ntm = blockIdx.x;
  int n = ntm / (TT * MM), r = ntm % (TT * MM), t = r / MM, m = r % MM;
  int tid = threadIdx.x;
  for (int i = tid; i < 3 * VV * VV; i += 256) {
    int k = i / (VV * VV), e = i % (VV * VV), tt = t + k - 1;
    Gs3[i] = (tt >= 0 && tt < TT) ? G[((size_t)((n * TT + tt) * MM + m)) * (VV * VV) + e] : 0.f;
  }
  for (int i = tid; i < VV * VV * 3; i += 256) wls[i] = adj_w[i];
  __syncthreads();
  for (int e = tid; e < VV * VV; e += 256) {
    int u = e / VV, o = e % VV;
    float a = adj_b[o];
#pragma unroll
    for (int i = 0; i < VV; ++i) {
      a = fmaf(Gs3[u * VV + i], wls[o * 75 + i * 3 + 0], a);
      a = fmaf(Gs3[VV * VV + u * VV + i], wls[o * 75 + i * 3 + 1], a);
      a = fmaf(Gs3[2 * VV * VV + u * VV + i], wls[o * 75 + i * 3 + 2], a);
    }
    gout[(size_t)ntm * (VV * VV) + e] = a;
  }
}

extern "C" void kernel_launch(void* const* d_in, const int* in_sizes, int n_in,
                              void* d_out, int out_size, void* d_ws, size_t ws_size,
                              hipStream_t stream) {
  const float* x     = (const float*)d_in[0];
  const float* G     = (const float*)d_in[1];
  const float* ej_w1 = (const float*)d_in[2];
  const float* ej_b1 = (const float*)d_in[3];
  const float* ej_w2 = (const float*)d_in[4];
  const float* ej_b2 = (const float*)d_in[5];
  const float* ef_w1 = (const float*)d_in[6];
  const float* ef_b1 = (const float*)d_in[7];
  const float* ef_w2 = (const float*)d_in[8];
  const float* ef_b2 = (const float*)d_in[9];
  const float* gcn_w = (const float*)d_in[10];
  const float* gcn_b = (const float*)d_in[11];
  const float* tcn_w = (const float*)d_in[12];
  const float* tcn_b = (const float*)d_in[13];
  const float* bn_g  = (const float*)d_in[14];
  const float* bn_b  = (const float*)d_in[15];
  const float* bn_m  = (const float*)d_in[16];
  const float* bn_v  = (const float*)d_in[17];
  const float* adj_w = (const float*)d_in[18];
  const float* adj_b = (const float*)d_in[19];
  float* out = (float*)d_out;
  float* ws  = (float*)d_ws;

  k0a_ej<<<1, 256, 0, stream>>>(ej_w1, ej_b1, ej_w2, ej_b2, gcn_w, tcn_b, bn_g, bn_b, bn_m, bn_v, ws);
  k0b_ef<<<TT, CO, 0, stream>>>(ef_w1, ef_b1, ef_w2, ef_b2, ws);
  k_wt2<<<(3 * CO * CO + 255) / 256, 256, 0, stream>>>(tcn_w, ws);
  k1_ct<<<TT, CO, 0, stream>>>(tcn_w, ws, ws + WS_CT);
  k_gcn<<<NN * TT * MM, 256, 0, stream>>>(x, G, gcn_w, gcn_b, ws + WS_EJW, ws);
  k_tcn<<<NN * MM * VV, 512, 0, stream>>>(ws, out);
  k_adj<<<NN * TT * MM, 256, 0, stream>>>(G, adj_w, adj_b, out + XOUT_ELEMS);
}

// Round 12
// 475.558 us; speedup vs baseline: 1.5880x; 1.0901x over previous
//
#include <hip/hip_runtime.h>

#define NN 64
#define TT 64
#define MM 2
#define VV 25
#define CI 64
#define CO 128
#define EMBH 64

typedef __attribute__((ext_vector_type(8))) short short8;
typedef __attribute__((ext_vector_type(4))) float f32x4;

// ws layout (float offsets)
#define WS_EJW 0          // 3200
#define WS_EF  3200       // 8192 (k0b->k1_ct; then reused: WGH/WGL)
#define WS_WGH 3200       // 8192 ushort = 4096 floats (gcn_w top, [o][c] bf16 hi)
#define WS_WGL 7296       // 4096 floats (lo)
#define WS_S   11392      // 128
#define WS_BC  11520      // 128
#define WS_CT  11648      // 8192
#define WS_WH  19840      // 24576 floats (tcn_w bf16 hi, [s][o][c])
#define WS_WL  44416      // 24576 floats
#define WS_HHI 68992      // 13107200 floats (h bf16 hi)
#define WS_HLO 13176192   // 13107200 floats (h bf16 lo)
#define XOUT_ELEMS 26214400

__device__ __forceinline__ unsigned short bf16_rne(float f) {
  unsigned u = __float_as_uint(f);
  unsigned r = u + 0x7FFFu + ((u >> 16) & 1u);
  return (unsigned short)(r >> 16);
}
__device__ __forceinline__ float bf16_to_f(unsigned short h) {
  return __uint_as_float((unsigned)h << 16);
}

// ---------------- k0a: ej MLP -> ejW fold, plus BN fold ----------------
__global__ void k0a_ej(const float* __restrict__ ej_w1, const float* __restrict__ ej_b1,
                       const float* __restrict__ ej_w2, const float* __restrict__ ej_b2,
                       const float* __restrict__ gcn_w, const float* __restrict__ tcn_b,
                       const float* __restrict__ bn_gamma, const float* __restrict__ bn_beta,
                       const float* __restrict__ bn_mean, const float* __restrict__ bn_var,
                       float* __restrict__ ws) {
  __shared__ float tmp1[VV * EMBH];
  __shared__ float ejs[VV * EMBH];
  int tid = threadIdx.x;
  for (int i = tid; i < VV * EMBH; i += 256)
    tmp1[i] = fmaxf(ej_w1[i] + ej_b1[i & 63], 0.f);
  __syncthreads();
  for (int i = tid; i < VV * EMBH; i += 256) {
    int v = i >> 6, c = i & 63;
    float a = ej_b2[c];
    for (int h = 0; h < EMBH; ++h) a = fmaf(tmp1[v * EMBH + h], ej_w2[h * CI + c], a);
    ejs[i] = fmaxf(a, 0.f);
  }
  __syncthreads();
  for (int i = tid; i < VV * CO; i += 256) {
    int v = i >> 7, o = i & 127;
    float a = 0.f;
    for (int c = 0; c < CI; ++c) a = fmaf(ejs[v * EMBH + c], gcn_w[(CI + c) * CO + o], a);
    ws[WS_EJW + i] = a;
  }
  if (tid < CO) {
    float s = bn_gamma[tid] * rsqrtf(bn_var[tid] + 1e-5f);
    ws[WS_S + tid] = s;
    ws[WS_BC + tid] = tcn_b[tid] * s + bn_beta[tid] - bn_mean[tid] * s;
  }
}

// ---------------- k0b: ef[t][o] ----------------
__global__ void k0b_ef(const float* __restrict__ ef_w1, const float* __restrict__ ef_b1,
                       const float* __restrict__ ef_w2, const float* __restrict__ ef_b2,
                       float* __restrict__ ws) {
  __shared__ float tf[EMBH];
  int t = blockIdx.x, o = threadIdx.x;
  if (o < EMBH) tf[o] = fmaxf(ef_w1[t * EMBH + o] + ef_b1[o], 0.f);
  __syncthreads();
  float a = ef_b2[o];
#pragma unroll
  for (int h = 0; h < EMBH; ++h) a = fmaf(tf[h], ef_w2[h * CO + o], a);
  ws[WS_EF + t * CO + o] = fmaxf(a, 0.f);
}

// ---------------- k_wt2: split tcn_w -> bf16 hi/lo, layout [s][o][c] ----------------
__global__ void k_wt2(const float* __restrict__ tcn_w, float* __restrict__ ws) {
  int j = blockIdx.x * 256 + threadIdx.x;
  if (j >= 3 * CO * CO) return;
  int s = j >> 14, rr = j & 16383, o = rr >> 7, c = rr & 127;
  float f = tcn_w[o * (CO * 3) + c * 3 + s];
  unsigned short hi = bf16_rne(f);
  float lo = f - bf16_to_f(hi);
  ((unsigned short*)(ws + WS_WH))[j] = hi;
  ((unsigned short*)(ws + WS_WL))[j] = bf16_rne(lo);
}

// ---------------- k_wg: split gcn_w top half -> [o][c] bf16 hi/lo (into dead EF region) ----------------
__global__ void k_wg(const float* __restrict__ gcn_w, float* __restrict__ ws) {
  int j = blockIdx.x * 256 + threadIdx.x;
  if (j >= CO * CI) return;
  int o = j >> 6, c = j & 63;
  float f = gcn_w[c * CO + o];
  unsigned short hi = bf16_rne(f);
  float lo = f - bf16_to_f(hi);
  ((unsigned short*)(ws + WS_WGH))[j] = hi;
  ((unsigned short*)(ws + WS_WGL))[j] = bf16_rne(lo);
}

// ---------------- k1_ct: ct[t][o] = conv(ef)[o,t]*s[o] + bc[o] ----------------
__global__ void k1_ct(const float* __restrict__ tcn_w, const float* __restrict__ ws_ro,
                      float* __restrict__ ct_out) {
  __shared__ float ef3[3 * CO];
  int t = blockIdx.x, o = threadIdx.x;
  for (int i = o; i < 3 * CO; i += 128) {
    int k = i >> 7, c = i & 127, tt = t + k - 1;
    ef3[i] = (tt >= 0 && tt < TT) ? ws_ro[WS_EF + tt * CO + c] : 0.f;
  }
  __syncthreads();
  const float* wp = tcn_w + o * (CO * 3);
  float a = 0.f;
  for (int c = 0; c < CO; ++c) {
    a = fmaf(ef3[c], wp[c * 3 + 0], a);
    a = fmaf(ef3[CO + c], wp[c * 3 + 1], a);
    a = fmaf(ef3[2 * CO + c], wp[c * 3 + 2], a);
  }
  ct_out[t * CO + o] = fmaf(a, ws_ro[WS_S + o], ws_ro[WS_BC + o]);
}

// ---------------- GCN v4: split-bf16 MFMA, per (n,t,m) ----------------
// GEMM1: P[v][o] = x[v][:]@Wtop[:, o] + ejW[v][o]   (M=32pad, N=128, K=64)
// GEMM2: h[u][o] = relu( G[u][:]@P[:, o] + b[o] )   (M=32pad, N=128, K=32pad)
__global__ void __launch_bounds__(256, 4) k_gcn(const float* __restrict__ x, const float* __restrict__ G,
                                                const float* __restrict__ gcn_b, float* __restrict__ ws) {
  __shared__ __align__(16) unsigned short xh[32 * 64], xl[32 * 64];   // [v][c], XOR-swizzled rows (128B pitch)
  __shared__ __align__(16) unsigned short Gh[32 * 40], Gl[32 * 40];   // [u][v], 80B pitch
  __shared__ __align__(16) unsigned short Ph[128 * 40], Pl[128 * 40]; // P^T [o][v], 80B pitch
  int ntm = blockIdx.x;
  int tid = threadIdx.x;
  int w = tid >> 6, l = tid & 63, lm = l & 15, lg = l >> 4;
  int o0 = w * 32;  // each of 4 waves owns 32 o-columns (2 n-tiles)

  // B-frags for GEMM1 (Wtop), from ws: [o][c] bf16 hi/lo
  const unsigned short* wgh = (const unsigned short*)(ws + WS_WGH);
  const unsigned short* wgl = (const unsigned short*)(ws + WS_WGL);
  short8 wfh[2][2], wfl[2][2];
#pragma unroll
  for (int nt = 0; nt < 2; ++nt)
#pragma unroll
    for (int ks = 0; ks < 2; ++ks) {
      int idx = (o0 + nt * 16 + lm) * CI + ks * 32 + lg * 8;
      wfh[nt][ks] = *(const short8*)(wgh + idx);
      wfl[nt][ks] = *(const short8*)(wgl + idx);
    }

  // zero x/G arrays (pads must be true zeros)
  {
    unsigned* xh32 = (unsigned*)xh; unsigned* xl32 = (unsigned*)xl;
    for (int i = tid; i < 1024; i += 256) { xh32[i] = 0u; xl32[i] = 0u; }
    unsigned* gh32 = (unsigned*)Gh; unsigned* gl32 = (unsigned*)Gl;
    for (int i = tid; i < 640; i += 256) { gh32[i] = 0u; gl32[i] = 0u; }
  }
  __syncthreads();
  // fill x (split to hi/lo, swizzled) and G (split, pitch-40)
  const float* xb = x + (size_t)ntm * (VV * CI);
  for (int i = tid; i < VV * CI; i += 256) {
    int v = i >> 6, c = i & 63;
    float f = xb[i];
    unsigned short hi = bf16_rne(f);
    float lo = f - bf16_to_f(hi);
    int elem = v * 64 + (((c * 2) ^ ((v & 7) << 4)) >> 1);
    xh[elem] = hi;
    xl[elem] = bf16_rne(lo);
  }
  const float* Gb = G + (size_t)ntm * (VV * VV);
  for (int i = tid; i < VV * VV; i += 256) {
    int u = i / VV, vc = i - u * VV;
    float f = Gb[i];
    unsigned short hi = bf16_rne(f);
    float lo = f - bf16_to_f(hi);
    Gh[u * 40 + vc] = hi;
    Gl[u * 40 + vc] = bf16_rne(lo);
  }
  __syncthreads();

  // ---- GEMM1 + P^T epilogue ----
  const float* ejW = ws + WS_EJW;
#pragma unroll
  for (int mt = 0; mt < 2; ++mt) {
#pragma unroll
    for (int nt = 0; nt < 2; ++nt) {
      f32x4 hh = {0.f, 0.f, 0.f, 0.f}, lh = {0.f, 0.f, 0.f, 0.f}, hl = {0.f, 0.f, 0.f, 0.f};
      int row = mt * 16 + lm, rbase = row * 128, sw = (row & 7) << 4;
#pragma unroll
      for (int ks = 0; ks < 2; ++ks) {
        int eo = (rbase + (((ks * 64 + lg * 16) ^ sw))) >> 1;
        short8 Ah = *(const short8*)(&xh[eo]);
        short8 Al = *(const short8*)(&xl[eo]);
        hh = __builtin_amdgcn_mfma_f32_16x16x32_bf16(Ah, wfh[nt][ks], hh, 0, 0, 0);
        lh = __builtin_amdgcn_mfma_f32_16x16x32_bf16(Al, wfh[nt][ks], lh, 0, 0, 0);
        hl = __builtin_amdgcn_mfma_f32_16x16x32_bf16(Ah, wfl[nt][ks], hl, 0, 0, 0);
      }
      int o = o0 + nt * 16 + lm;
      int vb = mt * 16 + lg * 4;
      unsigned short ph[4], pl[4];
#pragma unroll
      for (int r = 0; r < 4; ++r) {
        int v = vb + r;
        float e = (v < VV) ? ejW[v * CO + o] : 0.f;
        float acc = hh[r] + lh[r] + hl[r] + e;
        unsigned short hi = bf16_rne(acc);
        float lo = acc - bf16_to_f(hi);
        ph[r] = hi;
        pl[r] = bf16_rne(lo);
      }
      uint2 hv, lv;
      hv.x = (unsigned)ph[0] | ((unsigned)ph[1] << 16);
      hv.y = (unsigned)ph[2] | ((unsigned)ph[3] << 16);
      lv.x = (unsigned)pl[0] | ((unsigned)pl[1] << 16);
      lv.y = (unsigned)pl[2] | ((unsigned)pl[3] << 16);
      *(uint2*)(&Ph[o * 40 + vb]) = hv;
      *(uint2*)(&Pl[o * 40 + vb]) = lv;
    }
  }
  __syncthreads();

  // ---- GEMM2 + h epilogue ----
  unsigned short* hh_g = (unsigned short*)(ws + WS_HHI);
  unsigned short* hl_g = (unsigned short*)(ws + WS_HLO);
  size_t base = (size_t)ntm * (VV * CO);
#pragma unroll
  for (int mt = 0; mt < 2; ++mt) {
#pragma unroll
    for (int nt = 0; nt < 2; ++nt) {
      f32x4 hh = {0.f, 0.f, 0.f, 0.f}, lh = {0.f, 0.f, 0.f, 0.f}, hl = {0.f, 0.f, 0.f, 0.f};
      int ga = (mt * 16 + lm) * 40 + lg * 8;
      int pa = (o0 + nt * 16 + lm) * 40 + lg * 8;
      short8 Ah = *(const short8*)(&Gh[ga]);
      short8 Al = *(const short8*)(&Gl[ga]);
      short8 Bh = *(const short8*)(&Ph[pa]);
      short8 Bl = *(const short8*)(&Pl[pa]);
      hh = __builtin_amdgcn_mfma_f32_16x16x32_bf16(Ah, Bh, hh, 0, 0, 0);
      lh = __builtin_amdgcn_mfma_f32_16x16x32_bf16(Al, Bh, lh, 0, 0, 0);
      hl = __builtin_amdgcn_mfma_f32_16x16x32_bf16(Ah, Bl, hl, 0, 0, 0);
      int o = o0 + nt * 16 + lm;
      float bo = gcn_b[o];
#pragma unroll
      for (int r = 0; r < 4; ++r) {
        int u = mt * 16 + lg * 4 + r;
        if (u < VV) {
          float y = fmaxf(hh[r] + lh[r] + hl[r] + bo, 0.f);
          unsigned short hi = bf16_rne(y);
          float lo = y - bf16_to_f(hi);
          hh_g[base + u * CO + o] = hi;
          hl_g[base + u * CO + o] = bf16_rne(lo);
        }
      }
    }
  }
}

// ---------------- TCN v4: split-bf16 MFMA GEMM, per (n,m,v) ----------------
__global__ void __launch_bounds__(512) k_tcn(const float* __restrict__ ws_ro,
                                             float* __restrict__ out) {
  __shared__ __align__(16) unsigned short h2[2 * 68 * 128];  // hi @0, lo @8704; row = t+1
  int b = blockIdx.x;
  int n = b / (MM * VV), r = b % (MM * VV), m = r / VV, v = r % VV;
  int tid = threadIdx.x;
  const unsigned short* hh_g = (const unsigned short*)(ws_ro + WS_HHI);
  const unsigned short* hl_g = (const unsigned short*)(ws_ro + WS_HLO);
  size_t gbase = ((size_t)(n * TT * MM + m) * VV + v) * CO;
#pragma unroll
  for (int arr = 0; arr < 2; ++arr) {
    const unsigned short* src = arr ? hl_g : hh_g;
#pragma unroll
    for (int rep = 0; rep < 2; ++rep) {
      int task = rep * 512 + tid;
      int t = task >> 4, chunk = task & 15;
      int row = t + 1;
      int4 val = *(const int4*)(src + gbase + (size_t)t * (MM * VV * CO) + chunk * 8);
      int elem = arr * 8704 + row * 128 + ((((chunk * 16) ^ ((row & 7) << 4))) >> 1);
      *(int4*)(&h2[elem]) = val;
    }
  }
  if (tid < 64) {
    int arr = tid >> 5, rr = (tid >> 4) & 1, chunk = tid & 15;
    int row = rr ? 65 : 0;
    int elem = arr * 8704 + row * 128 + ((((chunk * 16) ^ ((row & 7) << 4))) >> 1);
    int4 z = {0, 0, 0, 0};
    *(int4*)(&h2[elem]) = z;
  }
  __syncthreads();
  int w = tid >> 6, l = tid & 63;
  int o0 = w * 16, lm = l & 15, lg = l >> 4;
  const unsigned short* wh_g = (const unsigned short*)(ws_ro + WS_WH);
  const unsigned short* wl_g = (const unsigned short*)(ws_ro + WS_WL);
  short8 bh[3][4], bl[3][4];
#pragma unroll
  for (int s = 0; s < 3; ++s)
#pragma unroll
    for (int ks = 0; ks < 4; ++ks) {
      int idx = (s * CO + o0 + lm) * CO + ks * 32 + lg * 8;
      bh[s][ks] = *(const short8*)(wh_g + idx);
      bl[s][ks] = *(const short8*)(wl_g + idx);
    }
  float so = ws_ro[WS_S + o0 + lm];
  float* ob = out + gbase;
  for (int tq = 0; tq < 4; ++tq) {
    f32x4 ahh = {0.f, 0.f, 0.f, 0.f}, alh = {0.f, 0.f, 0.f, 0.f}, ahl = {0.f, 0.f, 0.f, 0.f};
#pragma unroll
    for (int s = 0; s < 3; ++s) {
      int row = tq * 16 + lm + s;
      int rbase = row * 128, sw = (row & 7) << 4;
#pragma unroll
      for (int ks = 0; ks < 4; ++ks) {
        int eo = rbase + (((ks * 64 + lg * 16) ^ sw) >> 1);
        short8 Ah = *(const short8*)(&h2[eo]);
        short8 Al = *(const short8*)(&h2[8704 + eo]);
        ahh = __builtin_amdgcn_mfma_f32_16x16x32_bf16(Ah, bh[s][ks], ahh, 0, 0, 0);
        alh = __builtin_amdgcn_mfma_f32_16x16x32_bf16(Al, bh[s][ks], alh, 0, 0, 0);
        ahl = __builtin_amdgcn_mfma_f32_16x16x32_bf16(Ah, bl[s][ks], ahl, 0, 0, 0);
      }
    }
#pragma unroll
    for (int rr = 0; rr < 4; ++rr) {
      int t = tq * 16 + lg * 4 + rr;
      float acc = ahh[rr] + alh[rr] + ahl[rr];
      float y = fmaxf(fmaf(acc, so, ws_ro[WS_CT + t * CO + o0 + lm]), 0.f);
      ob[(size_t)t * (MM * VV * CO) + o0 + lm] = y;
    }
  }
}

// ---------------- ADJ ----------------
__global__ void k_adj(const float* __restrict__ G, const float* __restrict__ adj_w,
                      const float* __restrict__ adj_b, float* __restrict__ gout) {
  __shared__ float Gs3[3 * VV * VV];
  __shared__ float wls[VV * VV * 3];
  int ntm = blockIdx.x;
  int n = ntm / (TT * MM), r = ntm % (TT * MM), t = r / MM, m = r % MM;
  int tid = threadIdx.x;
  for (int i = tid; i < 3 * VV * VV; i += 256) {
    int k = i / (VV * VV), e = i % (VV * VV), tt = t + k - 1;
    Gs3[i] = (tt >= 0 && tt < TT) ? G[((size_t)((n * TT + tt) * MM + m)) * (VV * VV) + e] : 0.f;
  }
  for (int i = tid; i < VV * VV * 3; i += 256) wls[i] = adj_w[i];
  __syncthreads();
  for (int e = tid; e < VV * VV; e += 256) {
    int u = e / VV, o = e % VV;
    float a = adj_b[o];
#pragma unroll
    for (int i = 0; i < VV; ++i) {
      a = fmaf(Gs3[u * VV + i], wls[o * 75 + i * 3 + 0], a);
      a = fmaf(Gs3[VV * VV + u * VV + i], wls[o * 75 + i * 3 + 1], a);
      a = fmaf(Gs3[2 * VV * VV + u * VV + i], wls[o * 75 + i * 3 + 2], a);
    }
    gout[(size_t)ntm * (VV * VV) + e] = a;
  }
}

extern "C" void kernel_launch(void* const* d_in, const int* in_sizes, int n_in,
                              void* d_out, int out_size, void* d_ws, size_t ws_size,
                              hipStream_t stream) {
  const float* x     = (const float*)d_in[0];
  const float* G     = (const float*)d_in[1];
  const float* ej_w1 = (const float*)d_in[2];
  const float* ej_b1 = (const float*)d_in[3];
  const float* ej_w2 = (const float*)d_in[4];
  const float* ej_b2 = (const float*)d_in[5];
  const float* ef_w1 = (const float*)d_in[6];
  const float* ef_b1 = (const float*)d_in[7];
  const float* ef_w2 = (const float*)d_in[8];
  const float* ef_b2 = (const float*)d_in[9];
  const float* gcn_w = (const float*)d_in[10];
  const float* gcn_b = (const float*)d_in[11];
  const float* tcn_w = (const float*)d_in[12];
  const float* tcn_b = (const float*)d_in[13];
  const float* bn_g  = (const float*)d_in[14];
  const float* bn_b  = (const float*)d_in[15];
  const float* bn_m  = (const float*)d_in[16];
  const float* bn_v  = (const float*)d_in[17];
  const float* adj_w = (const float*)d_in[18];
  const float* adj_b = (const float*)d_in[19];
  float* out = (float*)d_out;
  float* ws  = (float*)d_ws;

  k0a_ej<<<1, 256, 0, stream>>>(ej_w1, ej_b1, ej_w2, ej_b2, gcn_w, tcn_b, bn_g, bn_b, bn_m, bn_v, ws);
  k0b_ef<<<TT, CO, 0, stream>>>(ef_w1, ef_b1, ef_w2, ef_b2, ws);
  k_wt2<<<(3 * CO * CO + 255) / 256, 256, 0, stream>>>(tcn_w, ws);
  k1_ct<<<TT, CO, 0, stream>>>(tcn_w, ws, ws + WS_CT);
  k_wg<<<(CO * CI + 255) / 256, 256, 0, stream>>>(gcn_w, ws);  // after k1_ct: reuses EF region
  k_gcn<<<NN * TT * MM, 256, 0, stream>>>(x, G, gcn_b, ws);
  k_tcn<<<NN * MM * VV, 512, 0, stream>>>(ws, out);
  k_adj<<<NN * TT * MM, 256, 0, stream>>>(G, adj_w, adj_b, out + XOUT_ELEMS);
}